// Round 1
// baseline (144.071 us; speedup 1.0000x reference)
//
#include <hip/hip_runtime.h>

#define NP 44
#define B  400000
#define B4 (B / 4)      // 100000 float4 groups per particle
#define BLK 256

__global__ __launch_bounds__(BLK) void fused_mlp_kernel(
    const float* __restrict__ X,    // (NP, 1, B)
    const float* __restrict__ W1,   // (NP, 4, 1)
    const float* __restrict__ W2,   // (NP, 8, 4)
    const float* __restrict__ W3,   // (NP, 4, 8)
    const float* __restrict__ W4,   // (NP, 1, 4)
    float* __restrict__ out)        // (NP, 1, B)
{
    const int l   = blockIdx.y;                       // particle index
    const int idx = blockIdx.x * BLK + threadIdx.x;   // float4 index within particle
    if (idx >= B4) return;

    // ---- Load this particle's 72 weights into registers (wave-uniform addresses,
    //      L1-broadcast; compiler may scalarize to s_load) ----
    const float* p1 = W1 + l * 4;
    const float* p2 = W2 + l * 32;
    const float* p3 = W3 + l * 32;
    const float* p4 = W4 + l * 4;

    float w1[4], w2[8][4], w3[4][8], w4[4];
#pragma unroll
    for (int i = 0; i < 4; ++i) w1[i] = p1[i];
#pragma unroll
    for (int i = 0; i < 8; ++i)
#pragma unroll
        for (int k = 0; k < 4; ++k) w2[i][k] = p2[i * 4 + k];
#pragma unroll
    for (int i = 0; i < 4; ++i)
#pragma unroll
        for (int k = 0; k < 8; ++k) w3[i][k] = p3[i * 8 + k];
#pragma unroll
    for (int i = 0; i < 4; ++i) w4[i] = p4[i];

    // ---- Coalesced float4 load of 4 batch elements ----
    const float4* Xp = (const float4*)(X + (size_t)l * B);
    float4*       Op = (float4*)(out + (size_t)l * B);

    float4 xv = Xp[idx];
    float xs[4] = {xv.x, xv.y, xv.z, xv.w};
    float res[4];

#pragma unroll
    for (int e = 0; e < 4; ++e) {
        const float x = xs[e];

        // layer 1: 1 -> 4, ReLU
        float h1[4];
#pragma unroll
        for (int i = 0; i < 4; ++i) h1[i] = fmaxf(w1[i] * x, 0.0f);

        // layer 2: 4 -> 8, ReLU
        float h2[8];
#pragma unroll
        for (int i = 0; i < 8; ++i) {
            float a = 0.0f;
#pragma unroll
            for (int k = 0; k < 4; ++k) a = fmaf(w2[i][k], h1[k], a);
            h2[i] = fmaxf(a, 0.0f);
        }

        // layer 3: 8 -> 4, ReLU
        float h3[4];
#pragma unroll
        for (int i = 0; i < 4; ++i) {
            float a = 0.0f;
#pragma unroll
            for (int k = 0; k < 8; ++k) a = fmaf(w3[i][k], h2[k], a);
            h3[i] = fmaxf(a, 0.0f);
        }

        // layer 4: 4 -> 1 (no ReLU)
        float a = 0.0f;
#pragma unroll
        for (int k = 0; k < 4; ++k) a = fmaf(w4[k], h3[k], a);
        res[e] = a;
    }

    Op[idx] = make_float4(res[0], res[1], res[2], res[3]);
}

extern "C" void kernel_launch(void* const* d_in, const int* in_sizes, int n_in,
                              void* d_out, int out_size, void* d_ws, size_t ws_size,
                              hipStream_t stream) {
    const float* X  = (const float*)d_in[0];
    const float* W1 = (const float*)d_in[1];
    const float* W2 = (const float*)d_in[2];
    const float* W3 = (const float*)d_in[3];
    const float* W4 = (const float*)d_in[4];
    float* out = (float*)d_out;

    dim3 grid((B4 + BLK - 1) / BLK, NP);   // (391, 44)
    fused_mlp_kernel<<<grid, BLK, 0, stream>>>(X, W1, W2, W3, W4, out);
}